// Round 12
// baseline (91.849 us; speedup 1.0000x reference)
//
#include <hip/hip_runtime.h>
#include <hip/hip_bf16.h>

#define N_NODES 100000
#define N_EDGES 1600000
#define D_IN    128
#define D_HID   16
#define D_OUT   32

#define BSHIFT 8
#define BNODES 256                 // nodes per bucket
#define NB 391                     // ceil(100000/256)
#define NBPAD 512
#define SCHUNK 4096                // edges per sort block
#define SBLOCKS 391                // ceil(1600000/4096)
#define MMBLOCKS 782               // 200K threads (2 nodes/thread, 4 jq lanes)
#define SLAB 4608                  // slab slots per bucket (mean 4096, +8 sigma)
#define NOSTRIDE 257               // node_off stride per bucket (256 + sentinel)

// shared-memory union layout for the fused kernel (bytes)
#define SS_HIST   0                // int[512]
#define SS_LBASE  2048             // int[512]
#define SS_GBASE  4096             // int[391] (pad to 1600)
#define SS_TSCAN  5696             // int[256]
#define SS_SORTED 6720             // unsigned[4096]
#define SS_BID    23104            // ushort[4096]
#define SS_BYTES  31296

// bf16x2 helpers -------------------------------------------------------------
__device__ inline float bf_lo(unsigned dw) { return __uint_as_float(dw << 16); }
__device__ inline float bf_hi(unsigned dw) { return __uint_as_float(dw & 0xffff0000u); }
__device__ inline unsigned bf_pack(float f0, float f1) {
    union { __hip_bfloat16 h[2]; unsigned u; } pu;
    pu.h[0] = __float2bfloat16(f0);
    pu.h[1] = __float2bfloat16(f1);
    return pu.u;
}
__device__ inline void acc8(float* a, uint4 w) {
    a[0] += bf_lo(w.x); a[1] += bf_hi(w.x);
    a[2] += bf_lo(w.y); a[3] += bf_hi(w.y);
    a[4] += bf_lo(w.z); a[5] += bf_hi(w.z);
    a[6] += bf_lo(w.w); a[7] += bf_hi(w.w);
}

// ---------------------------------------------------------------------------
// K0: init slab cursors (1 block, ~1us).
// ---------------------------------------------------------------------------
__global__ __launch_bounds__(512) void k_init(int* __restrict__ cursor) {
    int i = threadIdx.x;
    if (i < NB) cursor[i] = i * SLAB;
}

// ---------------------------------------------------------------------------
// K1 (mega): blocks [0, SBLOCKS) run the bucket-grouping counting sort;
// blocks [SBLOCKS, SBLOCKS+MMBLOCKS) run mm1 at 2 nodes/thread (halved
// LDS W-reads). The two halves read disjoint inputs and overlap on the GPU.
// ---------------------------------------------------------------------------
__global__ __launch_bounds__(256) void k_fused1(const float* __restrict__ feat,
                                                const float* __restrict__ W1,
                                                const int* __restrict__ src,
                                                const int* __restrict__ dst,
                                                int* __restrict__ cursor,
                                                unsigned* __restrict__ pairs,
                                                unsigned* __restrict__ Yu) {
    __shared__ char smem[SS_BYTES];
    int tid = threadIdx.x, blk = blockIdx.x;

    if (blk < SBLOCKS) {
        // ---------------- sortscatter path ----------------
        int* hist    = (int*)(smem + SS_HIST);
        int* lbase   = (int*)(smem + SS_LBASE);
        int* gbase   = (int*)(smem + SS_GBASE);
        int* tscan   = (int*)(smem + SS_TSCAN);
        unsigned* sorted = (unsigned*)(smem + SS_SORTED);
        unsigned short* bId = (unsigned short*)(smem + SS_BID);

        int base = blk * SCHUNK;
        int nval = N_EDGES - base;
        if (nval > SCHUNK) nval = SCHUNK;

        for (int i = tid; i < NBPAD; i += 256) hist[i] = 0;
        __syncthreads();

        int varr[16], barr[16];
#pragma unroll
        for (int k = 0; k < 16; ++k) {
            int e = base + k * 256 + tid;
            if (e < N_EDGES) {
                int s = src[e], d = dst[e];
                varr[k] = (s << BSHIFT) | (d & (BNODES - 1));
                int b = d >> BSHIFT;
                barr[k] = b;
                atomicAdd(&hist[b], 1);
            } else {
                barr[k] = -1;
            }
        }
        __syncthreads();

        int i0 = tid * 2;
        int h0 = hist[i0], h1 = hist[i0 + 1];
        int lsum = h0 + h1;
        tscan[tid] = lsum;
        __syncthreads();
#pragma unroll
        for (int off = 1; off < 256; off <<= 1) {
            int x = (tid >= off) ? tscan[tid - off] : 0;
            __syncthreads();
            tscan[tid] += x;
            __syncthreads();
        }
        int excl = tscan[tid] - lsum;
        lbase[i0 + 0] = excl;
        lbase[i0 + 1] = excl + h0;
        __syncthreads();

        for (int i = tid; i < NB; i += 256) {
            int c = hist[i];
            if (c > 0) gbase[i] = atomicAdd(&cursor[i], c);
        }
        __syncthreads();
        for (int i = tid; i < NBPAD; i += 256) hist[i] = 0;
        __syncthreads();

#pragma unroll
        for (int k = 0; k < 16; ++k) {
            int b = barr[k];
            if (b >= 0) {
                int r = atomicAdd(&hist[b], 1);
                int p = lbase[b] + r;
                sorted[p] = (unsigned)varr[k];
                bId[p] = (unsigned short)b;
            }
        }
        __syncthreads();

        for (int i = tid; i < nval; i += 256) {
            int b = bId[i];
            pairs[gbase[b] + (i - lbase[b])] = sorted[i];
        }
    } else {
        // ---------------- mm1 path (2 nodes/thread) ----------------
        float* sW = (float*)smem;           // 8 KB of the union
        for (int i = tid; i < D_IN * D_HID; i += 256) sW[i] = W1[i];
        __syncthreads();

        int gid = (blk - SBLOCKS) * 256 + tid;
        int p = gid >> 2;          // node pair
        int jq = gid & 3;          // output quad
        int n0 = p * 2, n1 = p * 2 + 1;
        if (n0 >= N_NODES) return;
        bool has1 = (n1 < N_NODES);

        const float4* f40 = (const float4*)(feat + (size_t)n0 * D_IN);
        const float4* f41 = (const float4*)(feat + (size_t)n1 * D_IN);
        const float4* sW4 = (const float4*)sW;

        float4 acc0 = make_float4(0.f, 0.f, 0.f, 0.f);
        float4 acc1 = make_float4(0.f, 0.f, 0.f, 0.f);
#pragma unroll 4
        for (int kq = 0; kq < 32; ++kq) {
            float4 f0 = f40[kq];
            float4 f1 = has1 ? f41[kq] : make_float4(0.f, 0.f, 0.f, 0.f);
            int k0 = kq * 4;
            float4 w0 = sW4[(k0 + 0) * 4 + jq];
            float4 w1 = sW4[(k0 + 1) * 4 + jq];
            float4 w2 = sW4[(k0 + 2) * 4 + jq];
            float4 w3 = sW4[(k0 + 3) * 4 + jq];
            acc0.x += f0.x * w0.x + f0.y * w1.x + f0.z * w2.x + f0.w * w3.x;
            acc0.y += f0.x * w0.y + f0.y * w1.y + f0.z * w2.y + f0.w * w3.y;
            acc0.z += f0.x * w0.z + f0.y * w1.z + f0.z * w2.z + f0.w * w3.z;
            acc0.w += f0.x * w0.w + f0.y * w1.w + f0.z * w2.w + f0.w * w3.w;
            acc1.x += f1.x * w0.x + f1.y * w1.x + f1.z * w2.x + f1.w * w3.x;
            acc1.y += f1.x * w0.y + f1.y * w1.y + f1.z * w2.y + f1.w * w3.y;
            acc1.z += f1.x * w0.z + f1.y * w1.z + f1.z * w2.z + f1.w * w3.z;
            acc1.w += f1.x * w0.w + f1.y * w1.w + f1.z * w2.w + f1.w * w3.w;
        }
        uint2 o0, o1;
        o0.x = bf_pack(acc0.x, acc0.y);
        o0.y = bf_pack(acc0.z, acc0.w);
        ((uint2*)(Yu + (size_t)n0 * 8))[jq] = o0;
        if (has1) {
            o1.x = bf_pack(acc1.x, acc1.y);
            o1.y = bf_pack(acc1.z, acc1.w);
            ((uint2*)(Yu + (size_t)n1 * 8))[jq] = o1;
        }
    }
}

// ---------------------------------------------------------------------------
// K2: per-bucket node sort (256 keys, 1 thread per key). In-place rewrite of
// pairs -> node-sorted plain src ids + node_off (stride-257 layout).
// ---------------------------------------------------------------------------
__global__ __launch_bounds__(256) void k_nodesort(const int* __restrict__ cursor,
                                                  unsigned* __restrict__ pairs,
                                                  int* __restrict__ node_off) {
    __shared__ unsigned buf[SLAB];      // 18 KB
    __shared__ int hist[BNODES];
    __shared__ int cur[BNODES];
    __shared__ int t[256];

    int tid = threadIdx.x, b = blockIdx.x;
    int beg = b * SLAB;
    int cnt = cursor[b] - beg;

    hist[tid] = 0;
    __syncthreads();

    for (int i = tid; i < cnt; i += 256) {
        unsigned p = pairs[beg + i];
        buf[i] = p;
        atomicAdd(&hist[p & (BNODES - 1)], 1);
    }
    __syncthreads();

    int v = hist[tid];
    t[tid] = v;
    __syncthreads();
#pragma unroll
    for (int off = 1; off < 256; off <<= 1) {
        int x = (tid >= off) ? t[tid - off] : 0;
        __syncthreads();
        t[tid] += x;
        __syncthreads();
    }
    int excl = t[tid] - v;
    cur[tid] = excl;
    node_off[b * NOSTRIDE + tid] = beg + excl;
    if (tid == 0) node_off[b * NOSTRIDE + BNODES] = beg + cnt;  // sentinel
    __syncthreads();

    for (int i = tid; i < cnt; i += 256) {
        unsigned p = buf[i];
        int pos = atomicAdd(&cur[p & (BNODES - 1)], 1);
        pairs[beg + pos] = p >> BSHIFT;    // plain src id, node-sorted
    }
}

// ---------------------------------------------------------------------------
// K3: layer-1 aggregation: 128 nodes/block, 2 lanes/node, uint4 (16B)
// gathers, 4-deep unroll. Register accumulation, fused bias+ReLU -> bf16 H1.
// ---------------------------------------------------------------------------
__global__ __launch_bounds__(256) void k_agg1(const int* __restrict__ node_off,
                                              const unsigned* __restrict__ csr,
                                              const uint4* __restrict__ Yu4,
                                              const float* __restrict__ bias1,
                                              uint4* __restrict__ H1u4) {
    int tid = threadIdx.x;
    int g = tid >> 1, c = tid & 1;
    int n = blockIdx.x * 128 + g;
    if (n >= N_NODES) return;
    int idx = n + (n >> 8);
    int beg = node_off[idx], end = node_off[idx + 1];

    float a[8] = {0,0,0,0,0,0,0,0}, b[8] = {0,0,0,0,0,0,0,0};
    int i = beg;
    for (; i + 3 < end; i += 4) {
        unsigned s0 = csr[i], s1 = csr[i + 1], s2 = csr[i + 2], s3 = csr[i + 3];
        uint4 w0 = Yu4[(size_t)s0 * 2 + c];
        uint4 w1 = Yu4[(size_t)s1 * 2 + c];
        uint4 w2 = Yu4[(size_t)s2 * 2 + c];
        uint4 w3 = Yu4[(size_t)s3 * 2 + c];
        acc8(a, w0); acc8(b, w1); acc8(a, w2); acc8(b, w3);
    }
    for (; i < end; ++i) {
        uint4 w = Yu4[(size_t)csr[i] * 2 + c];
        acc8(a, w);
    }
    uint4 o;
    float f0, f1;
    f0 = a[0] + b[0] + bias1[c * 8 + 0];
    f1 = a[1] + b[1] + bias1[c * 8 + 1];
    o.x = bf_pack(fmaxf(f0, 0.f), fmaxf(f1, 0.f));
    f0 = a[2] + b[2] + bias1[c * 8 + 2];
    f1 = a[3] + b[3] + bias1[c * 8 + 3];
    o.y = bf_pack(fmaxf(f0, 0.f), fmaxf(f1, 0.f));
    f0 = a[4] + b[4] + bias1[c * 8 + 4];
    f1 = a[5] + b[5] + bias1[c * 8 + 5];
    o.z = bf_pack(fmaxf(f0, 0.f), fmaxf(f1, 0.f));
    f0 = a[6] + b[6] + bias1[c * 8 + 6];
    f1 = a[7] + b[7] + bias1[c * 8 + 7];
    o.w = bf_pack(fmaxf(f0, 0.f), fmaxf(f1, 0.f));
    H1u4[(size_t)n * 2 + c] = o;
}

// ---------------------------------------------------------------------------
// K4: layer-2 aggregation (same gather structure) + fused mm2 epilogue.
// ---------------------------------------------------------------------------
__global__ __launch_bounds__(256) void k_agg2(const int* __restrict__ node_off,
                                              const unsigned* __restrict__ csr,
                                              const uint4* __restrict__ H1u4,
                                              const float* __restrict__ W2,
                                              const float* __restrict__ b2,
                                              float* __restrict__ out) {
    __shared__ float sacc[128][D_HID + 1];  // 8.7 KB
    __shared__ float sW2[D_HID * D_OUT];    // 2 KB
    __shared__ float sb2[D_OUT];
    int tid = threadIdx.x;
    for (int i2 = tid; i2 < D_HID * D_OUT; i2 += 256) sW2[i2] = W2[i2];
    if (tid < D_OUT) sb2[tid] = b2[tid];

    int g = tid >> 1, c = tid & 1;
    int n = blockIdx.x * 128 + g;

    float a[8] = {0,0,0,0,0,0,0,0}, b[8] = {0,0,0,0,0,0,0,0};
    if (n < N_NODES) {
        int idx = n + (n >> 8);
        int beg = node_off[idx], end = node_off[idx + 1];
        int i = beg;
        for (; i + 3 < end; i += 4) {
            unsigned s0 = csr[i], s1 = csr[i + 1], s2 = csr[i + 2], s3 = csr[i + 3];
            uint4 w0 = H1u4[(size_t)s0 * 2 + c];
            uint4 w1 = H1u4[(size_t)s1 * 2 + c];
            uint4 w2 = H1u4[(size_t)s2 * 2 + c];
            uint4 w3 = H1u4[(size_t)s3 * 2 + c];
            acc8(a, w0); acc8(b, w1); acc8(a, w2); acc8(b, w3);
        }
        for (; i < end; ++i) {
            uint4 w = H1u4[(size_t)csr[i] * 2 + c];
            acc8(a, w);
        }
    }
#pragma unroll
    for (int j = 0; j < 8; ++j)
        sacc[g][c * 8 + j] = a[j] + b[j];
    __syncthreads();

    // mm2: 128 nodes x 32 outputs = 4096 -> 16 per thread
    for (int t2 = tid; t2 < 128 * D_OUT; t2 += 256) {
        int gg = t2 >> 5, o = t2 & 31;
        int node = blockIdx.x * 128 + gg;
        if (node < N_NODES) {
            float acc = sb2[o];
#pragma unroll
            for (int j = 0; j < D_HID; ++j)
                acc = fmaf(sacc[gg][j], sW2[j * D_OUT + o], acc);
            out[(size_t)node * D_OUT + o] = acc;
        }
    }
}

// ---------------------------------------------------------------------------
extern "C" void kernel_launch(void* const* d_in, const int* in_sizes, int n_in,
                              void* d_out, int out_size, void* d_ws, size_t ws_size,
                              hipStream_t stream) {
    const float* feat = (const float*)d_in[0];
    const int*   src  = (const int*)d_in[1];
    const int*   dst  = (const int*)d_in[2];
    const float* W1   = (const float*)d_in[3];
    const float* b1   = (const float*)d_in[4];
    const float* W2   = (const float*)d_in[5];
    const float* b2   = (const float*)d_in[6];
    float* out = (float*)d_out;

    // ws layout (~14.0 MB):
    //   [0        , 7206912 )  pairs/csr slabs (NB * SLAB u32)
    //   [7208960  , +3.2M   )  Yu   (bf16x16 rows, packed, 16B aligned)
    //   [10408960 , +3.2M   )  H1u  (bf16x16 rows, packed, 16B aligned)
    //   [13608960 , +1.6K   )  cursor   (NB ints)
    //   [13613056 , +402K   )  node_off (NB*257 ints)
    char* base = (char*)d_ws;
    unsigned* pairs    = (unsigned*)(base);
    unsigned* Yu       = (unsigned*)(base + 7208960);
    unsigned* H1u      = (unsigned*)(base + 10408960);
    int*      cursor   = (int*)(base + 13608960);
    int*      node_off = (int*)(base + 13613056);

    // K0: slab cursor init (tiny)
    k_init  <<<1, 512, 0, stream>>>(cursor);
    // K1: fused mm1 (2 nodes/thread) + bucket-grouping counting sort
    k_fused1<<<SBLOCKS + MMBLOCKS, 256, 0, stream>>>(feat, W1, src, dst,
                                                     cursor, pairs, Yu);
    // K2: per-bucket node sort -> csr + node_off
    k_nodesort<<<NB, 256, 0, stream>>>(cursor, pairs, node_off);
    // K3: layer-1 aggregation (fused bias+ReLU)
    k_agg1  <<<(N_NODES + 127) / 128, 256, 0, stream>>>(node_off, pairs,
                                                        (const uint4*)Yu, b1,
                                                        (uint4*)H1u);
    // K4: layer-2 aggregation + fused mm2
    k_agg2  <<<(N_NODES + 127) / 128, 256, 0, stream>>>(node_off, pairs,
                                                        (const uint4*)H1u, W2, b2, out);
}